// Round 6
// baseline (846.495 us; speedup 1.0000x reference)
//
#include <hip/hip_runtime.h>

// DIAGNOSTIC ROUND 3: identical to R5's kernel except DRAIN_TICKS doubled
// (15000 -> 30000). Tick-doubling differencing: with R5's D1=348us,
//   f = 15000/(D2-348)   (s_memrealtime frequency)
//   S = 696 - D2         (drained-system store-phase, clock-independent)
// This discriminates: S~198 (burst congestion / f=100MHz), S~87 (issue-bound
// World A), S~45 (conveyor World B -> roofline). Store code, grid, and the
// zoff data-dependency are bit-identical to R5 so S is comparable.

#define T_PER_WAVE 2          // tiles per wave: 8192 tiles / 2 = 4096 waves
#define DRAIN_TICKS 30000ULL  // DOUBLED vs R5

__global__ __launch_bounds__(256) void sbc_kernel(const float* __restrict__ x,
                                                  float* __restrict__ out,
                                                  size_t mapsz) {
    const int lane = threadIdx.x & 63;               // column j
    const int wid  = blockIdx.x * 4 + (threadIdx.x >> 6);
    const int j    = lane;

    // Membership bitmask for column j: bit i set iff (i,j) is on the mask.
    const int sh = 63 - j;
    const unsigned long long mbits =
          (1ULL << j)
        | (0x7FFF000000000000ULL >> sh)
        | ((0x0000555500000000ULL >> sh) & 0x5555555555555555ULL)
        | ((0x0000000011111111ULL >> sh) & 0x1111111111111111ULL);

    const int tile0 = wid * T_PER_WAVE;

    // Preload this wave's tiles (256 B coalesced each).
    float xv[T_PER_WAVE];
#pragma unroll
    for (int tt = 0; tt < T_PER_WAVE; ++tt)
        xv[tt] = x[(size_t)(tile0 + tt) * 64 + j];

    // ---- pre-store drain spin: wait DRAIN_TICKS of the realtime clock ----
    const unsigned long long t0 = __builtin_amdgcn_s_memrealtime();
    unsigned guard = 0;
    while ((__builtin_amdgcn_s_memrealtime() - t0) < DRAIN_TICKS) {
        if (++guard >= (1u << 21)) break;            // hang guard
    }
    // Opaque zero derived from the spin result: forces all stores to be
    // data-dependent on spin completion (cannot be hoisted above it).
    int zoff;
    asm volatile("v_and_b32 %0, 0, %1" : "=v"(zoff) : "v"(guard));

#pragma unroll
    for (int tt = 0; tt < T_PER_WAVE; ++tt) {
        const int tile = tile0 + tt;
        float* __restrict__ bout = out + (size_t)tile * 4096 + zoff;
        float* __restrict__ cout = bout + mapsz;
        const float xj = xv[tt];
        float r = xj;   // finite init: masked lanes never see -inf
#pragma unroll
        for (int i = 63; i >= 0; --i) {
            const float xi = __shfl(xv[tt], i, 64);      // uniform -> v_readlane
            const float xs = (j >= i) ? xi : -INFINITY;
            r = fmaxf(r, xs);
            const bool on  = (mbits >> i) & 1ULL;
            const float s  = on ? 0.5f : 0.0f;
            const float s2 = on ? 1.0f : 0.0f;
            bout[i * 64 + j] = s * (xi + xj);
            cout[i * 64 + j] = s2 * r;
        }
        // mask: one copy per batch, owned by the tile with d==0
        if ((tile & 511) == 0) {
            float* __restrict__ mout = out + 2 * mapsz
                                     + (size_t)(tile >> 9) * 4096 + zoff;
#pragma unroll
            for (int i = 0; i < 64; ++i)
                mout[i * 64 + j] = ((mbits >> i) & 1ULL) ? 1.0f : 0.0f;
        }
    }
}

extern "C" void kernel_launch(void* const* d_in, const int* in_sizes, int n_in,
                              void* d_out, int out_size, void* d_ws, size_t ws_size,
                              hipStream_t stream) {
    const float* x = (const float*)d_in[0];
    float* out = (float*)d_out;
    const int N  = 64;
    const int BD = in_sizes[0] / N;                   // 8192 tiles
    const size_t mapsz = (size_t)BD * N * N;          // 33,554,432
    const int nwaves = BD / T_PER_WAVE;               // 4096
    sbc_kernel<<<dim3(nwaves / 4), dim3(256), 0, stream>>>(x, out, mapsz);
}

// Round 7
// 250.771 us; speedup vs baseline: 3.3756x; 3.3756x over previous
//
#include <hip/hip_runtime.h>

// FINAL KERNEL (restored R0 best: 250.1 us scored).
//
// Output layout (flat, reference return order), N=64, B=16, D=512:
//   [0,       mapsz)          boundary [B,D,N,N]
//   [mapsz, 2*mapsz)          content  [B,D,N,N]
//   [2*mapsz, 2*mapsz+B*N*N)  mask     [B,1,N,N] (0.0/1.0 f32)
//
// Identities: on member lines content[i,j] = max(x[i..j]),
// boundary[i,j] = 0.5*(x[i]+x[j]); diagonal is the len=1 case of both.
//
// ROOFLINE EVIDENCE (R4-R6 diagnostics):
//  - WRITE_SIZE = 262,400 KB = exactly the mandatory output bytes; FETCH ~1 MB
//    (no RFO, no double-write).
//  - Pre-drained store phase = ~46 us = 5.8 TB/s (R5/R6 tick-doubling
//    differencing; s_memrealtime measured ~50 MHz) -- the store code is at
//    the achievable write ceiling, not issue-bound.
//  - Timed period = fill poison (1.0748 GB) + output (268.7 MB) over HBM at
//    ~5.5 TB/s sustained mixed rate => ~245-250 us structural floor. The
//    harness's poison fill is 4x our output and not addressable from the
//    kernel. Three structurally different store schemes (dword/x4/nt,
//    2-8 waves/SIMD) all measured identical -- conveyor-bound, kernel-inert.

#define T_PER_WAVE 2   // tiles per wave: 8192 tiles / 2 = 4096 waves = 1024 blocks

__global__ __launch_bounds__(256) void sbc_kernel(const float* __restrict__ x,
                                                  float* __restrict__ out,
                                                  size_t mapsz) {
    const int lane = threadIdx.x & 63;               // column j
    const int wid  = blockIdx.x * 4 + (threadIdx.x >> 6);
    const int j    = lane;

    // Membership bitmask for column j: bit i set iff (i,j) is on the mask.
    //  diag: i==j
    //  g0: off=j-i in 1..15, any i          (rev const: bits 48..62)
    //  g1: off odd in 17..31, i even        (rev const: bits 32,34..46, & even-i)
    //  g2: off%4==3 in 35..63, i%4==0       (rev const: bits 0,4..28,  & i%4==0)
    const int sh = 63 - j;
    const unsigned long long mbits =
          (1ULL << j)
        | (0x7FFF000000000000ULL >> sh)
        | ((0x0000555500000000ULL >> sh) & 0x5555555555555555ULL)
        | ((0x0000000011111111ULL >> sh) & 0x1111111111111111ULL);

    const int tile0 = wid * T_PER_WAVE;

    // Preload this wave's tiles (256 B coalesced each), latencies overlapped.
    float xv[T_PER_WAVE];
#pragma unroll
    for (int tt = 0; tt < T_PER_WAVE; ++tt)
        xv[tt] = x[(size_t)(tile0 + tt) * 64 + j];

#pragma unroll
    for (int tt = 0; tt < T_PER_WAVE; ++tt) {
        const int tile = tile0 + tt;
        float* __restrict__ bout = out + (size_t)tile * 4096;
        float* __restrict__ cout = bout + mapsz;
        const float xj = xv[tt];
        float r = xj;   // finite init: masked lanes never see -inf
#pragma unroll
        for (int i = 63; i >= 0; --i) {
            const float xi = __shfl(xv[tt], i, 64);      // uniform -> v_readlane
            // running max of x[i..j], only once i enters [0, j]
            const float xs = (j >= i) ? xi : -INFINITY;
            r = fmaxf(r, xs);
            const bool on  = (mbits >> i) & 1ULL;
            const float s  = on ? 0.5f : 0.0f;
            const float s2 = on ? 1.0f : 0.0f;
            bout[i * 64 + j] = s * (xi + xj);
            cout[i * 64 + j] = s2 * r;
        }
        // mask: one copy per batch, owned by the tile with d==0
        if ((tile & 511) == 0) {
            float* __restrict__ mout = out + 2 * mapsz + (size_t)(tile >> 9) * 4096;
#pragma unroll
            for (int i = 0; i < 64; ++i)
                mout[i * 64 + j] = ((mbits >> i) & 1ULL) ? 1.0f : 0.0f;
        }
    }
}

extern "C" void kernel_launch(void* const* d_in, const int* in_sizes, int n_in,
                              void* d_out, int out_size, void* d_ws, size_t ws_size,
                              hipStream_t stream) {
    const float* x = (const float*)d_in[0];
    float* out = (float*)d_out;
    const int N  = 64;
    const int BD = in_sizes[0] / N;                   // 8192 tiles
    const size_t mapsz = (size_t)BD * N * N;          // 33,554,432
    const int nwaves = BD / T_PER_WAVE;               // 4096
    sbc_kernel<<<dim3(nwaves / 4), dim3(256), 0, stream>>>(x, out, mapsz);
}